// Round 1
// baseline (517.543 us; speedup 1.0000x reference)
//
#include <hip/hip_runtime.h>
#include <math.h>

#define B 16
#define C 256
#define CR 128
#define L 16384
#define NROW (B * C)          // 4096 rows of length L
#define THREADS 256
#define ITERS (L / 4 / THREADS)  // 16 float4 iters per thread

typedef float v4f __attribute__((ext_vector_type(4)));

// ---------------------------------------------------------------------------
// Kernel 1: per-(b,c) row mean over L. One block per row, coalesced float4.
// Forward row order (blockIdx 0..4095) -> fills L3 with x, newest rows last.
// ---------------------------------------------------------------------------
__global__ __launch_bounds__(THREADS) void row_mean_kernel(
    const float* __restrict__ x, float* __restrict__ s) {
    const int row = blockIdx.x;
    const int t = threadIdx.x;
    const float4* xr = (const float4*)(x + (size_t)row * L);

    float acc = 0.0f;
#pragma unroll
    for (int i = 0; i < ITERS; ++i) {
        float4 v = xr[t + i * THREADS];
        acc += (v.x + v.y) + (v.z + v.w);
    }
#pragma unroll
    for (int off = 32; off > 0; off >>= 1) acc += __shfl_down(acc, off, 64);

    __shared__ float wsum[THREADS / 64];
    if ((t & 63) == 0) wsum[t >> 6] = acc;
    __syncthreads();
    if (t == 0) {
        float tot = 0.0f;
#pragma unroll
        for (int w = 0; w < THREADS / 64; ++w) tot += wsum[w];
        s[row] = tot * (1.0f / (float)L);
    }
}

// ---------------------------------------------------------------------------
// Kernel 2: fused squeeze-excite MLP. ONE block, 256 threads.
//   h1 = gelu(BN1(s @ w1^T));  gate = sigmoid(BN2(h1 @ w2^T))
// Step A: thread (half=t>>7, r=t&127) computes h1raw[half*8..+7][r].
// Step B: thread t owns column c=t of h2 entirely -> BN2 is thread-local.
// Total work ~4096 FMA/thread on one CU: ~5-8 us, replaces two launches.
// ---------------------------------------------------------------------------
__global__ __launch_bounds__(256) void mlp_fused_kernel(
    const float* __restrict__ s, const float* __restrict__ w1,
    const float* __restrict__ g1, const float* __restrict__ b1,
    const float* __restrict__ w2, const float* __restrict__ g2,
    const float* __restrict__ b2, float* __restrict__ gate) {
    __shared__ float s_sh[B][C];    // 16 KiB
    __shared__ float h1_sh[B][CR];  // 8 KiB (raw, then gelu'd in place)
    const int t = threadIdx.x;

    for (int i = t; i < B * C; i += 256) s_sh[i >> 8][i & (C - 1)] = s[i];
    __syncthreads();

    // ---- h1raw = s @ w1^T ----
    {
        const int r = t & (CR - 1);
        const int half = t >> 7;  // 0 or 1 -> batches [0..7] or [8..15]
        float acc[8];
#pragma unroll
        for (int bb = 0; bb < 8; ++bb) acc[bb] = 0.0f;
        for (int k = 0; k < C; k += 4) {
            float4 w = *(const float4*)(w1 + r * C + k);
#pragma unroll
            for (int bb = 0; bb < 8; ++bb) {
                const float* a = &s_sh[half * 8 + bb][k];  // LDS broadcast
                acc[bb] = fmaf(a[0], w.x, acc[bb]);
                acc[bb] = fmaf(a[1], w.y, acc[bb]);
                acc[bb] = fmaf(a[2], w.z, acc[bb]);
                acc[bb] = fmaf(a[3], w.w, acc[bb]);
            }
        }
#pragma unroll
        for (int bb = 0; bb < 8; ++bb) h1_sh[half * 8 + bb][r] = acc[bb];
    }
    __syncthreads();

    // ---- BN1 over batch + exact-erf GELU, column r per thread ----
    if (t < CR) {
        float mu = 0.0f;
#pragma unroll
        for (int i = 0; i < B; ++i) mu += h1_sh[i][t];
        mu *= (1.0f / (float)B);
        float var = 0.0f;
#pragma unroll
        for (int i = 0; i < B; ++i) { float d = h1_sh[i][t] - mu; var = fmaf(d, d, var); }
        var *= (1.0f / (float)B);
        const float inv = rsqrtf(var + 1e-5f);
        const float gg = g1[t], bs = b1[t];
#pragma unroll
        for (int i = 0; i < B; ++i) {
            float v = (h1_sh[i][t] - mu) * inv * gg + bs;
            v = 0.5f * v * (1.0f + erff(v * 0.70710678118654752440f));
            h1_sh[i][t] = v;
        }
    }
    __syncthreads();

    // ---- h2[:,c] = h1 @ w2[c,:], BN2 thread-local, sigmoid -> gate ----
    {
        const int c = t;  // 0..255
        float acc2[B];
#pragma unroll
        for (int i = 0; i < B; ++i) acc2[i] = 0.0f;
        for (int k = 0; k < CR; k += 4) {
            float4 w = *(const float4*)(w2 + c * CR + k);
#pragma unroll
            for (int i = 0; i < B; ++i) {
                const float* a = &h1_sh[i][k];  // LDS broadcast
                acc2[i] = fmaf(a[0], w.x, acc2[i]);
                acc2[i] = fmaf(a[1], w.y, acc2[i]);
                acc2[i] = fmaf(a[2], w.z, acc2[i]);
                acc2[i] = fmaf(a[3], w.w, acc2[i]);
            }
        }
        float mu = 0.0f;
#pragma unroll
        for (int i = 0; i < B; ++i) mu += acc2[i];
        mu *= (1.0f / (float)B);
        float var = 0.0f;
#pragma unroll
        for (int i = 0; i < B; ++i) { float d = acc2[i] - mu; var = fmaf(d, d, var); }
        var *= (1.0f / (float)B);
        const float inv = rsqrtf(var + 1e-5f);
        const float gg = g2[c], bs = b2[c];
#pragma unroll
        for (int i = 0; i < B; ++i) {
            float v = (acc2[i] - mu) * inv * gg + bs;
            gate[i * C + c] = 1.0f / (1.0f + expf(-v));
        }
    }
}

// ---------------------------------------------------------------------------
// Kernel 3: out[b,c,:] = x[b,c,:] * gate[b,c].
// REVERSE row order: row_mean cached x in L3 (256 MiB == L3 capacity);
// reading newest-first (LIFO) maximizes L3 hits vs. cyclic-thrash forward scan.
// Non-temporal stores for out: don't let the write stream evict x from L3.
// ---------------------------------------------------------------------------
__global__ __launch_bounds__(THREADS) void scale_kernel(
    const float* __restrict__ x, const float* __restrict__ gate,
    float* __restrict__ out) {
    const int row = NROW - 1 - blockIdx.x;
    const int t = threadIdx.x;
    const float g = gate[row];
    const v4f* xr = (const v4f*)(x + (size_t)row * L);
    v4f* orow = (v4f*)(out + (size_t)row * L);
#pragma unroll
    for (int i = 0; i < ITERS; ++i) {
        v4f v = xr[t + i * THREADS];
        v *= g;
        __builtin_nontemporal_store(v, &orow[t + i * THREADS]);
    }
}

extern "C" void kernel_launch(void* const* d_in, const int* in_sizes, int n_in,
                              void* d_out, int out_size, void* d_ws, size_t ws_size,
                              hipStream_t stream) {
    const float* x  = (const float*)d_in[0];
    const float* w1 = (const float*)d_in[1];
    const float* g1 = (const float*)d_in[2];
    const float* b1 = (const float*)d_in[3];
    const float* w2 = (const float*)d_in[4];
    const float* g2 = (const float*)d_in[5];
    const float* b2 = (const float*)d_in[6];
    float* out = (float*)d_out;

    float* s    = (float*)d_ws;          // NROW floats   [B,C]
    float* gate = s + NROW;              // NROW floats   [B,C]

    row_mean_kernel<<<NROW, THREADS, 0, stream>>>(x, s);
    mlp_fused_kernel<<<1, 256, 0, stream>>>(s, w1, g1, b1, w2, g2, b2, gate);
    scale_kernel<<<NROW, THREADS, 0, stream>>>(x, gate, out);
}

// Round 2
// 506.871 us; speedup vs baseline: 1.0211x; 1.0211x over previous
//
#include <hip/hip_runtime.h>
#include <math.h>

#define B 16
#define C 256
#define CR 128
#define L 16384
#define NROW (B * C)          // 4096 rows of length L
#define THREADS 256
#define ITERS (L / 4 / THREADS)  // 16 float4 iters per thread

// ---------------------------------------------------------------------------
// Kernel 1: per-(b,c) row mean over L. One block per row, coalesced float4.
// Forward row order: fills L3 (x is exactly 256 MiB = L3 capacity), newest
// rows (high blockIdx) resident last -> scale_kernel reads them first.
// ---------------------------------------------------------------------------
__global__ __launch_bounds__(THREADS) void row_mean_kernel(
    const float* __restrict__ x, float* __restrict__ s) {
    const int row = blockIdx.x;
    const int t = threadIdx.x;
    const float4* xr = (const float4*)(x + (size_t)row * L);

    float acc = 0.0f;
#pragma unroll
    for (int i = 0; i < ITERS; ++i) {
        float4 v = xr[t + i * THREADS];
        acc += (v.x + v.y) + (v.z + v.w);
    }
#pragma unroll
    for (int off = 32; off > 0; off >>= 1) acc += __shfl_down(acc, off, 64);

    __shared__ float wsum[THREADS / 64];
    if ((t & 63) == 0) wsum[t >> 6] = acc;
    __syncthreads();
    if (t == 0) {
        float tot = 0.0f;
#pragma unroll
        for (int w = 0; w < THREADS / 64; ++w) tot += wsum[w];
        s[row] = tot * (1.0f / (float)L);
    }
}

// ---------------------------------------------------------------------------
// Kernel 2a: h1[b][r] = gelu(BN1(dot(s[b,:], w1[r,:]))). One block per r.
// 256 threads = 16 batches x 16 lanes; each lane covers 16 of 256 elements.
// (Parallel 128-block version — proven ~fast in the 503 us baseline; the
//  single-block fused variant serialized ~15 us onto one CU and regressed.)
// ---------------------------------------------------------------------------
__global__ __launch_bounds__(256) void mlp1_kernel(
    const float* __restrict__ s, const float* __restrict__ w1,
    const float* __restrict__ g1, const float* __restrict__ b1,
    float* __restrict__ h1) {
    const int r = blockIdx.x;      // 0..127
    const int t = threadIdx.x;     // 0..255
    const int b = t >> 4;          // 0..15
    const int j = t & 15;          // 0..15

    const float4* sv = (const float4*)(s + b * C) + j * 4;
    const float4* wv = (const float4*)(w1 + r * C) + j * 4;
    float acc = 0.0f;
#pragma unroll
    for (int k = 0; k < 4; ++k) {
        float4 a = sv[k], w = wv[k];
        acc += a.x * w.x + a.y * w.y + a.z * w.z + a.w * w.w;
    }
    // reduce over the 16-lane group
#pragma unroll
    for (int off = 8; off > 0; off >>= 1) acc += __shfl_down(acc, off, 16);

    __shared__ float h[B];
    if (j == 0) h[b] = acc;
    __syncthreads();

    // BN stats over batch (16 values) — every thread redundantly (cheap)
    float mu = 0.0f;
#pragma unroll
    for (int i = 0; i < B; ++i) mu += h[i];
    mu *= (1.0f / (float)B);
    float var = 0.0f;
#pragma unroll
    for (int i = 0; i < B; ++i) { float d = h[i] - mu; var = fmaf(d, d, var); }
    var *= (1.0f / (float)B);
    const float inv = rsqrtf(var + 1e-5f);

    if (t < B) {
        float v = (h[t] - mu) * inv * g1[r] + b1[r];
        v = 0.5f * v * (1.0f + erff(v * 0.70710678118654752440f));  // exact-erf GELU
        h1[t * CR + r] = v;
    }
}

// ---------------------------------------------------------------------------
// Kernel 2b: gate[b][c] = sigmoid(BN2(dot(h1[b,:], w2[c,:]))). One block per c.
// 128 threads = 16 batches x 8 lanes; each lane covers 16 of 128 elements.
// ---------------------------------------------------------------------------
__global__ __launch_bounds__(128) void mlp2_kernel(
    const float* __restrict__ h1, const float* __restrict__ w2,
    const float* __restrict__ g2, const float* __restrict__ b2,
    float* __restrict__ gate) {
    const int c = blockIdx.x;      // 0..255
    const int t = threadIdx.x;     // 0..127
    const int b = t >> 3;          // 0..15
    const int j = t & 7;           // 0..7

    const float4* hv = (const float4*)(h1 + b * CR) + j * 4;
    const float4* wv = (const float4*)(w2 + c * CR) + j * 4;
    float acc = 0.0f;
#pragma unroll
    for (int k = 0; k < 4; ++k) {
        float4 a = hv[k], w = wv[k];
        acc += a.x * w.x + a.y * w.y + a.z * w.z + a.w * w.w;
    }
#pragma unroll
    for (int off = 4; off > 0; off >>= 1) acc += __shfl_down(acc, off, 8);

    __shared__ float h[B];
    if (j == 0) h[b] = acc;
    __syncthreads();

    float mu = 0.0f;
#pragma unroll
    for (int i = 0; i < B; ++i) mu += h[i];
    mu *= (1.0f / (float)B);
    float var = 0.0f;
#pragma unroll
    for (int i = 0; i < B; ++i) { float d = h[i] - mu; var = fmaf(d, d, var); }
    var *= (1.0f / (float)B);
    const float inv = rsqrtf(var + 1e-5f);

    if (t < B) {
        float v = (h[t] - mu) * inv * g2[c] + b2[c];
        gate[t * C + c] = 1.0f / (1.0f + expf(-v));
    }
}

// ---------------------------------------------------------------------------
// Kernel 3: out[b,c,:] = x[b,c,:] * gate[b,c].
// REVERSE row order (LIFO vs. row_mean's fill order): the most-recently
// cached x rows are read first, before out-write allocations evict them.
// Plain stores (nt store suspected of hurting on the memory-side LLC in R1).
// ---------------------------------------------------------------------------
__global__ __launch_bounds__(THREADS) void scale_kernel(
    const float* __restrict__ x, const float* __restrict__ gate,
    float* __restrict__ out) {
    const int row = NROW - 1 - blockIdx.x;
    const int t = threadIdx.x;
    const float g = gate[row];
    const float4* xr = (const float4*)(x + (size_t)row * L);
    float4* orow = (float4*)(out + (size_t)row * L);
#pragma unroll
    for (int i = 0; i < ITERS; ++i) {
        float4 v = xr[t + i * THREADS];
        v.x *= g; v.y *= g; v.z *= g; v.w *= g;
        orow[t + i * THREADS] = v;
    }
}

extern "C" void kernel_launch(void* const* d_in, const int* in_sizes, int n_in,
                              void* d_out, int out_size, void* d_ws, size_t ws_size,
                              hipStream_t stream) {
    const float* x  = (const float*)d_in[0];
    const float* w1 = (const float*)d_in[1];
    const float* g1 = (const float*)d_in[2];
    const float* b1 = (const float*)d_in[3];
    const float* w2 = (const float*)d_in[4];
    const float* g2 = (const float*)d_in[5];
    const float* b2 = (const float*)d_in[6];
    float* out = (float*)d_out;

    float* s    = (float*)d_ws;          // NROW floats   [B,C]
    float* h1   = s + NROW;              // B*CR floats   [B,CR]
    float* gate = h1 + B * CR;           // NROW floats   [B,C]

    row_mean_kernel<<<NROW, THREADS, 0, stream>>>(x, s);
    mlp1_kernel<<<CR, 256, 0, stream>>>(s, w1, g1, b1, h1);
    mlp2_kernel<<<C, 128, 0, stream>>>(h1, w2, g2, b2, gate);
    scale_kernel<<<NROW, THREADS, 0, stream>>>(x, gate, out);
}